// Round 1
// baseline (4061.421 us; speedup 1.0000x reference)
//
#include <hip/hip_runtime.h>

#define T_SEQ 64
#define NV 4096
#define NE 65536
#define CIN 128
#define H2 512
#define HO 256
#define NEG_FLT (-3.402823466e38f)

// ---------------- workspace layout ----------------
struct Lay {
  size_t z, c, zn, cn, Bc1, Bc2, cnt, fill, rowptr, deginv, csr, agg1, h, mh, partial, total;
};
static Lay mk_layout(int tc){
  Lay L; size_t o = 0;
  auto tk = [&](size_t b){ size_t p = o; o += ((b + 255) & ~(size_t)255); return p; };
  L.z       = tk((size_t)T_SEQ * HO * 4);
  L.c       = tk((size_t)T_SEQ * HO * 4);
  L.zn      = tk((size_t)T_SEQ * 4);
  L.cn      = tk((size_t)T_SEQ * 4);
  L.Bc1     = tk((size_t)256 * 512 * 4);
  L.Bc2     = tk((size_t)512 * 512 * 4);
  L.cnt     = tk((size_t)tc * NV * 4);
  L.fill    = tk((size_t)tc * NV * 4);
  L.rowptr  = tk((size_t)tc * (NV + 1) * 4);
  L.deginv  = tk((size_t)tc * NV * 4);
  L.csr     = tk((size_t)tc * NE * 4);
  L.agg1    = tk((size_t)tc * NV * CIN * 4);
  L.h       = tk((size_t)tc * NV * H2 * 4);
  L.mh      = tk((size_t)tc * NV * H2 * 4);
  L.partial = tk((size_t)tc * 128 * HO * 4);
  L.total = o; return L;
}

// ---------------- small kernels ----------------
__global__ void k_init_out(float* out){
  int i = threadIdx.x;
  if (i < 2) out[i] = 0.0f;
}

__global__ void k_prep_B(const float* __restrict__ W1l, const float* __restrict__ W1r,
                         const float* __restrict__ W2l, const float* __restrict__ W2r,
                         float* __restrict__ Bc1, float* __restrict__ Bc2){
  int i = blockIdx.x * 256 + threadIdx.x;
  if (i < 256 * 512){
    int k = i >> 9, n = i & 511;
    Bc1[i] = (k < 128) ? W1l[k * 512 + n] : W1r[(k - 128) * 512 + n];
  } else {
    int j = i - 256 * 512;
    if (j < 512 * 512){
      int k = j >> 9, n = j & 511;
      Bc2[j] = (n < 256) ? W2l[k * 256 + n] : W2r[k * 256 + (n - 256)];
    }
  }
}

__global__ void k_zero(int* p, int n){
  int i = blockIdx.x * 256 + threadIdx.x;
  if (i < n) p[i] = 0;
}

__global__ void k_count(const int* __restrict__ ei, int t0, int tc, int* __restrict__ cnt){
  int i = blockIdx.x * 256 + threadIdx.x;
  if (i >= tc * NE) return;
  int tl = i >> 16, e = i & (NE - 1);
  int dst = ei[(size_t)(t0 + tl) * 2 * NE + NE + e];
  atomicAdd(&cnt[tl * NV + dst], 1);
}

__global__ void k_scan(const int* __restrict__ cnt, int* __restrict__ rowptr,
                       float* __restrict__ deginv){
  int tl = blockIdx.x, tid = threadIdx.x;
  __shared__ int s[256];
  int vals[16]; int sum = 0;
  const int* cb = cnt + tl * NV + tid * 16;
  #pragma unroll
  for (int i = 0; i < 16; i++){ vals[i] = cb[i]; sum += vals[i]; }
  s[tid] = sum; __syncthreads();
  for (int off = 1; off < 256; off <<= 1){
    int v = (tid >= off) ? s[tid - off] : 0;
    __syncthreads();
    s[tid] += v;
    __syncthreads();
  }
  int ex = s[tid] - sum;
  int* rp = rowptr + tl * (NV + 1) + tid * 16;
  float* dv = deginv + tl * NV + tid * 16;
  #pragma unroll
  for (int i = 0; i < 16; i++){
    rp[i] = ex; ex += vals[i];
    int d = vals[i] < 1 ? 1 : vals[i];
    dv[i] = 1.0f / (float)d;
  }
  if (tid == 255) rowptr[tl * (NV + 1) + NV] = ex;
}

__global__ void k_fill(const int* __restrict__ ei, int t0, int tc,
                       const int* __restrict__ rowptr, int* __restrict__ fill,
                       int* __restrict__ csr){
  int i = blockIdx.x * 256 + threadIdx.x;
  if (i >= tc * NE) return;
  int tl = i >> 16, e = i & (NE - 1);
  const int* eit = ei + (size_t)(t0 + tl) * 2 * NE;
  int src = eit[e], dst = eit[NE + e];
  int pos = atomicAdd(&fill[tl * NV + dst], 1);
  csr[tl * NE + rowptr[tl * (NV + 1) + dst] + pos] = src;
}

// conv1 aggregation: one wave per (t, v); lanes cover 128 ch as float2
__global__ __launch_bounds__(256) void k_agg1(const float* __restrict__ x, int t0, int tc,
                       const int* __restrict__ rowptr, const int* __restrict__ csr,
                       const float* __restrict__ deginv, float* __restrict__ agg1){
  int w = (blockIdx.x * 256 + threadIdx.x) >> 6;
  int lane = threadIdx.x & 63;
  if (w >= tc * NV) return;
  int tl = w >> 12, v = w & (NV - 1);
  const float2* xt = (const float2*)(x + (size_t)(t0 + tl) * NV * CIN);
  int beg = rowptr[tl * (NV + 1) + v], end = rowptr[tl * (NV + 1) + v + 1];
  const int* cs = csr + tl * NE;
  float ax = 0.f, ay = 0.f;
  for (int j = beg; j < end; j++){
    int s = cs[j];
    float2 xv = xt[(size_t)s * 64 + lane];
    ax += xv.x; ay += xv.y;
  }
  float di = deginv[tl * NV + v];
  float2 o; o.x = ax * di; o.y = ay * di;
  ((float2*)agg1)[(size_t)w * 64 + lane] = o;
}

// fp32 tiled GEMM: C[M x 512] = [Aa|Ab] (K-split at ksplit) @ B[Kt x 512] (+bias, relu)
// 128x128 tile, BK=32, 256 threads, 8x8 per thread (split 4+4 register tile)
__global__ __launch_bounds__(256) void k_gemm(
    const float* __restrict__ Aa, const float* __restrict__ Ab, int ksplit, int lda,
    const float* __restrict__ B, int Kt,
    const float* __restrict__ bias, int do_relu,
    float* __restrict__ C){
  __shared__ float As[32][132];
  __shared__ float Bs[32][132];
  int tid = threadIdx.x;
  int bm = blockIdx.x >> 2;
  int bn = blockIdx.x & 3;   // bn fastest: 4 consecutive blocks share the A panel (L2/L3 reuse)
  size_t row0 = (size_t)bm * 128;
  int col0 = bn * 128;
  int tm4 = (tid & 15) * 4;
  int tn4 = (tid >> 4) * 4;
  float acc[8][8];
  #pragma unroll
  for (int i = 0; i < 8; i++)
    #pragma unroll
    for (int j = 0; j < 8; j++) acc[i][j] = 0.f;

  for (int k0 = 0; k0 < Kt; k0 += 32){
    const float* Ap; int kk;
    if (k0 < ksplit){ Ap = Aa; kk = k0; } else { Ap = Ab; kk = k0 - ksplit; }
    #pragma unroll
    for (int i = 0; i < 4; i++){
      int s = tid + 256 * i;          // 0..1023
      int r = s >> 3;                 // 0..127
      int kq = (s & 7) << 2;          // 0..28
      float4 v = *(const float4*)(Ap + (row0 + r) * lda + kk + kq);
      As[kq + 0][r] = v.x; As[kq + 1][r] = v.y; As[kq + 2][r] = v.z; As[kq + 3][r] = v.w;
    }
    #pragma unroll
    for (int i = 0; i < 4; i++){
      int s = tid + 256 * i;
      int kr = s >> 5;                // 0..31
      int nq = (s & 31) << 2;         // 0..124
      *(float4*)&Bs[kr][nq] = *(const float4*)(B + (size_t)(k0 + kr) * 512 + col0 + nq);
    }
    __syncthreads();
    #pragma unroll
    for (int kk2 = 0; kk2 < 32; kk2++){
      float a[8], b[8];
      *(float4*)&a[0] = *(const float4*)&As[kk2][tm4];
      *(float4*)&a[4] = *(const float4*)&As[kk2][tm4 + 64];
      *(float4*)&b[0] = *(const float4*)&Bs[kk2][tn4];
      *(float4*)&b[4] = *(const float4*)&Bs[kk2][tn4 + 64];
      #pragma unroll
      for (int i = 0; i < 8; i++)
        #pragma unroll
        for (int j = 0; j < 8; j++)
          acc[i][j] = fmaf(a[i], b[j], acc[i][j]);
    }
    __syncthreads();
  }
  float bv[8];
  #pragma unroll
  for (int j = 0; j < 8; j++){
    int col = col0 + tn4 + ((j < 4) ? j : 64 + (j - 4));
    bv[j] = bias ? bias[col] : 0.f;
  }
  #pragma unroll
  for (int i = 0; i < 8; i++){
    size_t row = row0 + tm4 + ((i < 4) ? i : 64 + (i - 4));
    float* Crow = C + row * 512 + col0;
    float o[8];
    #pragma unroll
    for (int j = 0; j < 8; j++){
      float v = acc[i][j] + bv[j];
      if (do_relu) v = fmaxf(v, 0.f);
      o[j] = v;
    }
    float4 v0; v0.x = o[0]; v0.y = o[1]; v0.z = o[2]; v0.w = o[3];
    float4 v1; v1.x = o[4]; v1.y = o[5]; v1.z = o[6]; v1.w = o[7];
    *(float4*)(Crow + tn4) = v0;
    *(float4*)(Crow + tn4 + 64) = v1;
  }
}

// conv2 aggregation + finalize + per-block partial max-pool.
// block = 4 waves; each wave handles 8 nodes; lane covers 256 ch as float4.
__global__ __launch_bounds__(256) void k_conv2agg(
    const float* __restrict__ mh, const int* __restrict__ rowptr,
    const int* __restrict__ csr, const float* __restrict__ deginv,
    const float* __restrict__ b2l, float* __restrict__ partial){
  int blk = blockIdx.x;
  int tl = blk >> 7, nb = blk & 127;
  int wid = threadIdx.x >> 6, lane = threadIdx.x & 63;
  const float4* m4 = (const float4*)mh;   // row = 128 float4 (512 floats)
  const int* rp = rowptr + tl * (NV + 1);
  const int* cs = csr + tl * NE;
  float4 bb = ((const float4*)b2l)[lane];
  float4 vmax; vmax.x = NEG_FLT; vmax.y = NEG_FLT; vmax.z = NEG_FLT; vmax.w = NEG_FLT;
  int v0 = nb * 32 + wid * 8;
  for (int q = 0; q < 8; q++){
    int v = v0 + q;
    int beg = rp[v], end = rp[v + 1];
    float4 acc; acc.x = 0.f; acc.y = 0.f; acc.z = 0.f; acc.w = 0.f;
    for (int j = beg; j < end; j++){
      int s = cs[j];
      float4 mv = m4[(size_t)(tl * NV + s) * 128 + lane];
      acc.x += mv.x; acc.y += mv.y; acc.z += mv.z; acc.w += mv.w;
    }
    float di = deginv[tl * NV + v];
    float4 hr = m4[(size_t)(tl * NV + v) * 128 + 64 + lane];
    float4 val;
    val.x = acc.x * di + bb.x + hr.x;
    val.y = acc.y * di + bb.y + hr.y;
    val.z = acc.z * di + bb.z + hr.z;
    val.w = acc.w * di + bb.w + hr.w;
    vmax.x = fmaxf(vmax.x, val.x); vmax.y = fmaxf(vmax.y, val.y);
    vmax.z = fmaxf(vmax.z, val.z); vmax.w = fmaxf(vmax.w, val.w);
  }
  __shared__ float4 sm[4][64];
  sm[wid][lane] = vmax;
  __syncthreads();
  if (wid == 0){
    float4 a = sm[0][lane], b = sm[1][lane], c = sm[2][lane], d = sm[3][lane];
    float4 r;
    r.x = fmaxf(fmaxf(a.x, b.x), fmaxf(c.x, d.x));
    r.y = fmaxf(fmaxf(a.y, b.y), fmaxf(c.y, d.y));
    r.z = fmaxf(fmaxf(a.z, b.z), fmaxf(c.z, d.z));
    r.w = fmaxf(fmaxf(a.w, b.w), fmaxf(c.w, d.w));
    ((float4*)partial)[((size_t)(tl * 128 + nb)) * 64 + lane] = r;
  }
}

__global__ void k_pool(const float* __restrict__ partial, int t0, int tc,
                       float* __restrict__ z, float* __restrict__ zn){
  int tl = blockIdx.x, c = threadIdx.x;
  float m = NEG_FLT;
  for (int b = 0; b < 128; b++)
    m = fmaxf(m, partial[((size_t)(tl * 128 + b)) * HO + c]);
  z[(t0 + tl) * HO + c] = m;
  __shared__ float s[256];
  s[c] = m * m; __syncthreads();
  for (int off = 128; off > 0; off >>= 1){
    if (c < off) s[c] += s[c + off];
    __syncthreads();
  }
  if (c == 0) zn[t0 + tl] = sqrtf(s[0]);
}

__global__ void k_gru(const float* __restrict__ z, const float* __restrict__ Wih,
                      const float* __restrict__ bih, const float* __restrict__ bhh,
                      float* __restrict__ c, float* __restrict__ cn, float* __restrict__ out){
  int s0 = blockIdx.x, j = threadIdx.x;
  __shared__ float zs[256];
  __shared__ float ss[256];
  zs[j] = z[s0 * HO + j];
  __syncthreads();
  const float* wr = Wih + (size_t)j * HO;
  const float* wu = Wih + (size_t)(HO + j) * HO;
  const float* wn = Wih + (size_t)(2 * HO + j) * HO;
  float gr = bih[j], gu = bih[HO + j], gn = bih[2 * HO + j];
  for (int k = 0; k < HO; k++){
    float zv = zs[k];
    gr = fmaf(zv, wr[k], gr);
    gu = fmaf(zv, wu[k], gu);
    gn = fmaf(zv, wn[k], gn);
  }
  float r = 1.f / (1.f + expf(-(gr + bhh[j])));
  float u = 1.f / (1.f + expf(-(gu + bhh[HO + j])));
  float n = tanhf(gn + r * bhh[2 * HO + j]);
  float cv = (1.f - u) * n;
  c[s0 * HO + j] = cv;
  if (s0 < 44) out[2 + s0 * HO + j] = cv;
  ss[j] = cv * cv; __syncthreads();
  for (int off = 128; off > 0; off >>= 1){
    if (j < off) ss[j] += ss[j + off];
    __syncthreads();
  }
  if (j == 0) cn[s0] = sqrtf(ss[0]);
}

// CPC: 36 blocks (one per t_sample). 32 groups of 8 threads, each a 256-dot.
__global__ void k_cpc(const float* __restrict__ z, const float* __restrict__ c,
                      const float* __restrict__ zn, const float* __restrict__ cn,
                      float* __restrict__ out){
  int tt = blockIdx.x;
  int ts = 8 + tt;
  int tid = threadIdx.x;
  __shared__ float ct[256];
  __shared__ float tot[32];
  ct[tid] = c[ts * HO + tid];
  __syncthreads();
  int g = tid >> 3, r = tid & 7;
  int i = g >> 3, j = g & 7;
  int idx = ts + ((j == 0) ? (i + 1) : (i + j + 10));
  const float* zr = z + idx * HO;
  float s = 0.f;
  for (int k = r; k < HO; k += 8) s = fmaf(zr[k], ct[k], s);
  s += __shfl_down(s, 4, 8);
  s += __shfl_down(s, 2, 8);
  s += __shfl_down(s, 1, 8);
  if (r == 0){
    float den = fmaxf(zn[idx], 1e-8f) * fmaxf(cn[ts], 1e-8f);
    tot[g] = s / den;
  }
  __syncthreads();
  if (tid < 4){
    const float* tr = tot + tid * 8;
    float m = tr[0];
    for (int q = 1; q < 8; q++) m = fmaxf(m, tr[q]);
    float se = 0.f;
    for (int q = 0; q < 8; q++) se += expf(tr[q] - m);
    float lse = m + logf(se);
    float nce = (lse - tr[0]) * (1.0f / 144.0f);
    float corr = (tr[0] == m) ? (1.0f / 144.0f) : 0.f;
    atomicAdd(&out[0], nce);
    atomicAdd(&out[1], corr);
  }
}

// ---------------- launch ----------------
extern "C" void kernel_launch(void* const* d_in, const int* in_sizes, int n_in,
                              void* d_out, int out_size, void* d_ws, size_t ws_size,
                              hipStream_t stream){
  const float* x   = (const float*)d_in[0];
  const int*   ei  = (const int*)  d_in[1];
  const float* W1l = (const float*)d_in[2];
  const float* b1l = (const float*)d_in[3];
  const float* W1r = (const float*)d_in[4];
  const float* W2l = (const float*)d_in[5];
  const float* b2l = (const float*)d_in[6];
  const float* W2r = (const float*)d_in[7];
  const float* Wih = (const float*)d_in[8];
  const float* bih = (const float*)d_in[10];
  const float* bhh = (const float*)d_in[11];
  float* out = (float*)d_out;

  int tc = 64;
  while (tc > 1 && mk_layout(tc).total > ws_size) tc >>= 1;
  Lay L = mk_layout(tc);
  char* w = (char*)d_ws;
  float* zB   = (float*)(w + L.z);
  float* cB   = (float*)(w + L.c);
  float* znB  = (float*)(w + L.zn);
  float* cnB  = (float*)(w + L.cn);
  float* Bc1  = (float*)(w + L.Bc1);
  float* Bc2  = (float*)(w + L.Bc2);
  int*   cnt  = (int*)  (w + L.cnt);
  int*   fill = (int*)  (w + L.fill);
  int*   rp   = (int*)  (w + L.rowptr);
  float* dinv = (float*)(w + L.deginv);
  int*   csr  = (int*)  (w + L.csr);
  float* agg1 = (float*)(w + L.agg1);
  float* hB   = (float*)(w + L.h);
  float* mhB  = (float*)(w + L.mh);
  float* part = (float*)(w + L.partial);

  hipLaunchKernelGGL(k_init_out, dim3(1), dim3(64), 0, stream, out);
  hipLaunchKernelGGL(k_prep_B, dim3(1536), dim3(256), 0, stream, W1l, W1r, W2l, W2r, Bc1, Bc2);

  for (int t0 = 0; t0 < T_SEQ; t0 += tc){
    int nE = tc * NE;
    hipLaunchKernelGGL(k_zero, dim3((tc * NV + 255) / 256), dim3(256), 0, stream, cnt, tc * NV);
    hipLaunchKernelGGL(k_zero, dim3((tc * NV + 255) / 256), dim3(256), 0, stream, fill, tc * NV);
    hipLaunchKernelGGL(k_count, dim3((nE + 255) / 256), dim3(256), 0, stream, ei, t0, tc, cnt);
    hipLaunchKernelGGL(k_scan, dim3(tc), dim3(256), 0, stream, cnt, rp, dinv);
    hipLaunchKernelGGL(k_fill, dim3((nE + 255) / 256), dim3(256), 0, stream, ei, t0, tc, rp, fill, csr);
    hipLaunchKernelGGL(k_agg1, dim3(tc * NV / 4), dim3(256), 0, stream, x, t0, tc, rp, csr, dinv, agg1);
    // conv1 GEMM: h = relu([agg1 | x_t0] @ Bc1 + b1l)
    hipLaunchKernelGGL(k_gemm, dim3(tc * 128), dim3(256), 0, stream,
                       agg1, x + (size_t)t0 * NV * CIN, 128, CIN,
                       Bc1, 256, b1l, 1, hB);
    // conv2 GEMM: mh = h @ Bc2 (cols 0..255 = m, 256..511 = hr)
    hipLaunchKernelGGL(k_gemm, dim3(tc * 128), dim3(256), 0, stream,
                       hB, hB, 1 << 30, H2,
                       Bc2, 512, (const float*)nullptr, 0, mhB);
    hipLaunchKernelGGL(k_conv2agg, dim3(tc * 128), dim3(256), 0, stream,
                       mhB, rp, csr, dinv, b2l, part);
    hipLaunchKernelGGL(k_pool, dim3(tc), dim3(256), 0, stream, part, t0, tc, zB, znB);
  }

  hipLaunchKernelGGL(k_gru, dim3(T_SEQ), dim3(256), 0, stream, zB, Wih, bih, bhh, cB, cnB, out);
  hipLaunchKernelGGL(k_cpc, dim3(36), dim3(256), 0, stream, zB, cB, znB, cnB, out);
  (void)in_sizes; (void)n_in; (void)out_size;
}